// Round 5
// baseline (548.254 us; speedup 1.0000x reference)
//
#include <hip/hip_runtime.h>

#define N_NODES 50000
#define M_PAD   50048          // nodes padded to multiple of 64
#define N_EDGES 800000
#define E_PAD   1000000        // >= N_EDGES + 3*N_NODES (4-padded segments)
#define DIN 256
#define DH  128
#define NL  1000
#define NL_PAD 1024

typedef unsigned short ushort_t;
typedef __attribute__((ext_vector_type(8))) short bf16x8;
typedef __attribute__((ext_vector_type(4))) float f32x4;
typedef __attribute__((ext_vector_type(4))) unsigned int u32x4;

__device__ __forceinline__ ushort_t f32_to_bf16_rne(float f) {
    unsigned int u = __float_as_uint(f);
    unsigned int r = (u + 0x7FFFu + ((u >> 16) & 1u)) >> 16;
    return (ushort_t)r;
}
// packs (lo,hi) f32 -> 2x bf16 in one instr (no builtin on gfx950; inline asm)
__device__ __forceinline__ unsigned cvt_pk_bf16(float lo, float hi) {
    unsigned r;
    asm("v_cvt_pk_bf16_f32 %0, %1, %2" : "=v"(r) : "v"(lo), "v"(hi));
    return r;
}
__device__ __forceinline__ float bf16_lo(unsigned u) { return __uint_as_float(u << 16); }
__device__ __forceinline__ float bf16_hi(unsigned u) { return __uint_as_float(u & 0xFFFF0000u); }

// ---------------- fused B-operand pack (fragment-contiguous) ----------------
__device__ __forceinline__ void pack_one(const float* __restrict__ W, ushort_t* __restrict__ Bp,
                                         int K, int Nreal, int t) {
    const int CHN = K / 32;
    int lane = t & 63;
    int c = (t >> 6) % CHN;
    int nt = (t >> 6) / CHN;
    int n = nt * 16 + (lane & 15);
    int kb = c * 32 + (lane >> 4) * 8;
    ushort_t* p = Bp + (size_t)t * 8;
#pragma unroll
    for (int j = 0; j < 8; ++j)
        p[j] = (n < Nreal) ? f32_to_bf16_rne(W[(size_t)(kb + j) * Nreal + n]) : (ushort_t)0;
}

#define T_IN  ((DH / 16) * (DIN / 32) * 64)        // 4096
#define T_L   ((DH / 16) * (DH / 32) * 64)         // 2048
#define T_OUT ((NL_PAD / 16) * (DH / 32) * 64)     // 16384
#define T_ALL (T_IN + 2 * T_L + T_OUT)             // 24576
#define EB    ((N_EDGES + 255) / 256)              // 3125
#define PB    (T_ALL / 256)                        // 96

// ---------------- CSR build ----------------

// blocks [0, EB): degree count.  blocks [EB, EB+PB): weight packing (independent).
__global__ void count_pack_kernel(const int* __restrict__ dst, int* __restrict__ deg,
                                  const float* __restrict__ W_in, const float* __restrict__ W1,
                                  const float* __restrict__ W2, const float* __restrict__ W_out,
                                  ushort_t* __restrict__ Bp_in, ushort_t* __restrict__ Bp_1,
                                  ushort_t* __restrict__ Bp_2, ushort_t* __restrict__ Bp_out) {
    if (blockIdx.x < EB) {
        int e = blockIdx.x * blockDim.x + threadIdx.x;
        if (e < N_EDGES) atomicAdd(&deg[dst[e]], 1);
    } else {
        int tid = (blockIdx.x - EB) * blockDim.x + threadIdx.x;
        if (tid < T_IN) pack_one(W_in, Bp_in, DIN, DH, tid);
        else if (tid < T_IN + T_L) pack_one(W1, Bp_1, DH, DH, tid - T_IN);
        else if (tid < T_IN + 2 * T_L) pack_one(W2, Bp_2, DH, DH, tid - T_IN - T_L);
        else if (tid < T_ALL) pack_one(W_out, Bp_out, DH, NL, tid - T_IN - 2 * T_L);
    }
}

// Wave-atomic segment allocation: each node gets a 4-padded disjoint segment
// (order nondeterministic, contents deterministic). Zeroes only gap records.
__global__ __launch_bounds__(256) void alloc_kernel(
    int* __restrict__ deg_cur,        // in: degree, out: 0 (reused as cur)
    int* __restrict__ gcount,
    int* __restrict__ off_s, int* __restrict__ off_pe,
    int4* __restrict__ er)
{
    const int node = blockIdx.x * blockDim.x + threadIdx.x;
    const int lane = threadIdx.x & 63;
    const bool ok = node < N_NODES;
    int d  = ok ? deg_cur[node] : 0;
    int pd = (d + 3) & ~3;
    int pref = pd;
#pragma unroll
    for (int o = 1; o < 64; o <<= 1) {
        int v = __shfl_up(pref, o);
        if (lane >= o) pref += v;
    }
    int tot = __shfl(pref, 63);
    int base = 0;
    if (lane == 63) base = atomicAdd(gcount, tot);
    base = __shfl(base, 63);
    const int start = base + pref - pd;
    if (ok) {
        off_s[node]  = start;
        off_pe[node] = start + pd;
        deg_cur[node] = 0;                    // becomes scatter's cur
        for (int k = d; k < pd; ++k)          // zero gap records only
            er[start + k] = make_int4(0, 0, 0, 0);
    }
}

// Scatter edges into dst-sorted 16-B records: {src, ppi_bits, self_bits, 0}.
// One dwordx4 store per edge -> one RMW line instead of two.
__global__ void scatter_kernel(const int* __restrict__ dst, const int* __restrict__ src,
                               const float* __restrict__ self_w, const float* __restrict__ ppi_w,
                               const int* __restrict__ off_s, int* __restrict__ cur,
                               int4* __restrict__ er) {
    int e = blockIdx.x * blockDim.x + threadIdx.x;
    if (e < N_EDGES) {
        int d = dst[e];
        int p = off_s[d] + atomicAdd(&cur[d], 1);
        er[p] = make_int4(src[e], __float_as_int(ppi_w[e]), __float_as_int(self_w[e]), 0);
    }
}

// ---------------- input GEMM (reads f32 x, converts in-register) ------------
__global__ __launch_bounds__(256) void mfma_in_kernel(
    const float* __restrict__ x, const ushort_t* __restrict__ Bp,
    const float* __restrict__ bias, ushort_t* __restrict__ hb)
{
    constexpr int CHN = DIN / 32;                      // 8
    const int lane = threadIdx.x & 63;
    const int w    = threadIdx.x >> 6;
    const int r0   = blockIdx.y * 64;
    const int lr   = lane & 15;
    const int lq   = lane >> 4;

    bf16x8 bf[4][CHN];
#pragma unroll
    for (int t = 0; t < 4; ++t) {
        const int row = r0 + t * 16 + lr;
        const float* p = x + (size_t)row * DIN + lq * 8;
        const bool ok = row < N_NODES;
#pragma unroll
        for (int c = 0; c < CHN; ++c) {
            u32x4 uu = {0u, 0u, 0u, 0u};
            if (ok) {
                float4 f0 = ((const float4*)(p + c * 32))[0];
                float4 f1 = ((const float4*)(p + c * 32))[1];
                uu.x = cvt_pk_bf16(f0.x, f0.y);
                uu.y = cvt_pk_bf16(f0.z, f0.w);
                uu.z = cvt_pk_bf16(f1.x, f1.y);
                uu.w = cvt_pk_bf16(f1.z, f1.w);
            }
            bf[t][c] = __builtin_bit_cast(bf16x8, uu);
        }
    }

#pragma unroll
    for (int g = 0; g < 2; ++g) {
        const int dt = g * 4 + w;
        f32x4 acc[4] = {f32x4{0,0,0,0}, f32x4{0,0,0,0}, f32x4{0,0,0,0}, f32x4{0,0,0,0}};
#pragma unroll
        for (int c = 0; c < CHN; ++c) {
            bf16x8 afrag = *(const bf16x8*)(Bp + ((size_t)(dt * CHN + c) * 64 + lane) * 8);
#pragma unroll
            for (int t = 0; t < 4; ++t)
                acc[t] = __builtin_amdgcn_mfma_f32_16x16x32_bf16(afrag, bf[t][c], acc[t], 0, 0, 0);
        }
        const int d0 = dt * 16 + lq * 4;
        const float4 b4 = *(const float4*)(bias + d0);
#pragma unroll
        for (int t = 0; t < 4; ++t) {
            const int node = r0 + t * 16 + lr;
            float v[4];
            v[0] = fmaxf(acc[t][0] + b4.x, 0.f);
            v[1] = fmaxf(acc[t][1] + b4.y, 0.f);
            v[2] = fmaxf(acc[t][2] + b4.z, 0.f);
            v[3] = fmaxf(acc[t][3] + b4.w, 0.f);
            uint2 pp;
            pp.x = cvt_pk_bf16(v[0], v[1]);
            pp.y = cvt_pk_bf16(v[2], v[3]);
            *(uint2*)(hb + (size_t)node * DH + d0) = pp;
        }
    }
}

// ---------------- fused layer: aggregate (LDS) + hidden GEMM ----------------
// Block = 64 nodes, 4 waves. Phase 1: wave w aggregates nodes w*16..w*16+15
// (2 dims/lane) into LDS. Phase 2: MFMA tile with node fragments from LDS.
// LDS row stride 68 words (272 B = 17x16B): b128 fragment reads spread exactly
// 8 lanes per 4-bank group (conflict-free); phase-1 word stores are 2-way (free).
__global__ __launch_bounds__(256) void fused_layer_kernel(
    const ushort_t* __restrict__ hb_in,
    const int* __restrict__ off_s, const int* __restrict__ off_pe,
    const int4* __restrict__ er, const ushort_t* __restrict__ Bp,
    const float* __restrict__ bias, ushort_t* __restrict__ hb_out)
{
    __shared__ unsigned aggL[64][68];
    __shared__ unsigned resL[64][68];
    const int lane = threadIdx.x & 63;
    const int w    = threadIdx.x >> 6;
    const int r0   = blockIdx.y * 64;
    const int t    = lane;

    // ---- phase 1: aggregation ----
    for (int n16 = 0; n16 < 16; ++n16) {
        const int row = w * 16 + n16;
        const int node = r0 + row;
        float aa0 = 0.f, aa1 = 0.f, rr0 = 0.f, rr1 = 0.f;
        if (node < N_NODES) {
            const int lo = off_s[node], hi = off_pe[node];
            int i = lo;
            for (; i + 8 <= hi; i += 8) {
                const int4 rA = er[i],     rB = er[i + 1], rC = er[i + 2], rD = er[i + 3];
                const int4 rE = er[i + 4], rF = er[i + 5], rG = er[i + 6], rH = er[i + 7];
                unsigned u0 = *(const unsigned*)(hb_in + (size_t)rA.x * DH + 2 * t);
                unsigned u1 = *(const unsigned*)(hb_in + (size_t)rB.x * DH + 2 * t);
                unsigned u2 = *(const unsigned*)(hb_in + (size_t)rC.x * DH + 2 * t);
                unsigned u3 = *(const unsigned*)(hb_in + (size_t)rD.x * DH + 2 * t);
                unsigned u4 = *(const unsigned*)(hb_in + (size_t)rE.x * DH + 2 * t);
                unsigned u5 = *(const unsigned*)(hb_in + (size_t)rF.x * DH + 2 * t);
                unsigned u6 = *(const unsigned*)(hb_in + (size_t)rG.x * DH + 2 * t);
                unsigned u7 = *(const unsigned*)(hb_in + (size_t)rH.x * DH + 2 * t);
                float a0 = bf16_lo(u0), b0 = bf16_hi(u0);
                float a1 = bf16_lo(u1), b1 = bf16_hi(u1);
                float a2 = bf16_lo(u2), b2 = bf16_hi(u2);
                float a3 = bf16_lo(u3), b3 = bf16_hi(u3);
                float a4 = bf16_lo(u4), b4 = bf16_hi(u4);
                float a5 = bf16_lo(u5), b5 = bf16_hi(u5);
                float a6 = bf16_lo(u6), b6 = bf16_hi(u6);
                float a7 = bf16_lo(u7), b7 = bf16_hi(u7);
                float pA = __int_as_float(rA.y), sA = __int_as_float(rA.z);
                float pB = __int_as_float(rB.y), sB = __int_as_float(rB.z);
                float pC = __int_as_float(rC.y), sC = __int_as_float(rC.z);
                float pD = __int_as_float(rD.y), sD = __int_as_float(rD.z);
                float pE = __int_as_float(rE.y), sE = __int_as_float(rE.z);
                float pF = __int_as_float(rF.y), sF = __int_as_float(rF.z);
                float pG = __int_as_float(rG.y), sG = __int_as_float(rG.z);
                float pH = __int_as_float(rH.y), sH = __int_as_float(rH.z);
                aa0 += pA * a0 + pB * a1 + pC * a2 + pD * a3
                     + pE * a4 + pF * a5 + pG * a6 + pH * a7;
                aa1 += pA * b0 + pB * b1 + pC * b2 + pD * b3
                     + pE * b4 + pF * b5 + pG * b6 + pH * b7;
                rr0 += sA * a0 + sB * a1 + sC * a2 + sD * a3
                     + sE * a4 + sF * a5 + sG * a6 + sH * a7;
                rr1 += sA * b0 + sB * b1 + sC * b2 + sD * b3
                     + sE * b4 + sF * b5 + sG * b6 + sH * b7;
            }
            for (; i < hi; i += 4) {
                const int4 rA = er[i], rB = er[i + 1], rC = er[i + 2], rD = er[i + 3];
                unsigned u0 = *(const unsigned*)(hb_in + (size_t)rA.x * DH + 2 * t);
                unsigned u1 = *(const unsigned*)(hb_in + (size_t)rB.x * DH + 2 * t);
                unsigned u2 = *(const unsigned*)(hb_in + (size_t)rC.x * DH + 2 * t);
                unsigned u3 = *(const unsigned*)(hb_in + (size_t)rD.x * DH + 2 * t);
                float a0 = bf16_lo(u0), b0 = bf16_hi(u0);
                float a1 = bf16_lo(u1), b1 = bf16_hi(u1);
                float a2 = bf16_lo(u2), b2 = bf16_hi(u2);
                float a3 = bf16_lo(u3), b3 = bf16_hi(u3);
                float pA = __int_as_float(rA.y), sA = __int_as_float(rA.z);
                float pB = __int_as_float(rB.y), sB = __int_as_float(rB.z);
                float pC = __int_as_float(rC.y), sC = __int_as_float(rC.z);
                float pD = __int_as_float(rD.y), sD = __int_as_float(rD.z);
                aa0 += pA * a0 + pB * a1 + pC * a2 + pD * a3;
                aa1 += pA * b0 + pB * b1 + pC * b2 + pD * b3;
                rr0 += sA * a0 + sB * a1 + sC * a2 + sD * a3;
                rr1 += sA * b0 + sB * b1 + sC * b2 + sD * b3;
            }
        }
        aggL[row][t] = cvt_pk_bf16(aa0, aa1);
        resL[row][t] = cvt_pk_bf16(rr0, rr1);
    }
    __syncthreads();

    // ---- phase 2: GEMM (node fragments from LDS) ----
    const int lr = lane & 15;
    const int lq = lane >> 4;
#pragma unroll
    for (int g = 0; g < 2; ++g) {
        const int dt = g * 4 + w;
        f32x4 acc[4] = {f32x4{0,0,0,0}, f32x4{0,0,0,0}, f32x4{0,0,0,0}, f32x4{0,0,0,0}};
#pragma unroll
        for (int c = 0; c < 4; ++c) {
            bf16x8 afrag = *(const bf16x8*)(Bp + ((size_t)(dt * 4 + c) * 64 + lane) * 8);
#pragma unroll
            for (int tt = 0; tt < 4; ++tt) {
                bf16x8 bfrag = *(const bf16x8*)&aggL[tt * 16 + lr][lq * 4 + c * 16];
                acc[tt] = __builtin_amdgcn_mfma_f32_16x16x32_bf16(afrag, bfrag, acc[tt], 0, 0, 0);
            }
        }
        const int d0 = dt * 16 + lq * 4;
        const float4 b4 = *(const float4*)(bias + d0);
#pragma unroll
        for (int tt = 0; tt < 4; ++tt) {
            const int node = r0 + tt * 16 + lr;
            float v[4];
            v[0] = fmaxf(acc[tt][0] + b4.x, 0.f);
            v[1] = fmaxf(acc[tt][1] + b4.y, 0.f);
            v[2] = fmaxf(acc[tt][2] + b4.z, 0.f);
            v[3] = fmaxf(acc[tt][3] + b4.w, 0.f);
            const unsigned rw0 = resL[tt * 16 + lr][(d0 >> 1)];
            const unsigned rw1 = resL[tt * 16 + lr][(d0 >> 1) + 1];
            v[0] += bf16_lo(rw0); v[1] += bf16_hi(rw0);
            v[2] += bf16_lo(rw1); v[3] += bf16_hi(rw1);
            uint2 pp;
            pp.x = cvt_pk_bf16(v[0], v[1]);
            pp.y = cvt_pk_bf16(v[2], v[3]);
            *(uint2*)(hb_out + (size_t)node * DH + d0) = pp;
        }
    }
}

// ---------------- output GEMM with LDS-staged contiguous stores -------------
__global__ __launch_bounds__(256) void mfma_out_kernel(
    const ushort_t* __restrict__ hb, const ushort_t* __restrict__ Bp,
    const float* __restrict__ bias, float* __restrict__ out)
{
    constexpr int CHN = DH / 32;                       // 4
    __shared__ float cst[64][260];                     // 65 KB
    const int lane = threadIdx.x & 63;
    const int w    = threadIdx.x >> 6;
    const int r0   = blockIdx.y * 64;
    const int lr   = lane & 15;
    const int lq   = lane >> 4;

    bf16x8 bf[4][CHN];
#pragma unroll
    for (int t = 0; t < 4; ++t) {
        const ushort_t* p = hb + (size_t)(r0 + t * 16 + lr) * DH + lq * 8;
#pragma unroll
        for (int c = 0; c < CHN; ++c)
            bf[t][c] = *(const bf16x8*)(p + c * 32);
    }

#pragma unroll
    for (int g = 0; g < 4; ++g) {
        const int dt = (blockIdx.x * 4 + g) * 4 + w;   // global 16-label tile
        f32x4 acc[4] = {f32x4{0,0,0,0}, f32x4{0,0,0,0}, f32x4{0,0,0,0}, f32x4{0,0,0,0}};
#pragma unroll
        for (int c = 0; c < CHN; ++c) {
            bf16x8 afrag = *(const bf16x8*)(Bp + ((size_t)(dt * CHN + c) * 64 + lane) * 8);
#pragma unroll
            for (int t = 0; t < 4; ++t)
                acc[t] = __builtin_amdgcn_mfma_f32_16x16x32_bf16(afrag, bf[t][c], acc[t], 0, 0, 0);
        }

        const int d0 = dt * 16 + lq * 4;               // global label index
        float bv[4];
        if (d0 + 3 < NL) {
            const float4 b4 = *(const float4*)(bias + d0);
            bv[0] = b4.x; bv[1] = b4.y; bv[2] = b4.z; bv[3] = b4.w;
        } else {
#pragma unroll
            for (int i = 0; i < 4; ++i) bv[i] = (d0 + i < NL) ? bias[d0 + i] : 0.f;
        }
        const int cl = ((g * 4 + w) * 16) + lq * 4;    // local col in the 256-wide tile
#pragma unroll
        for (int t = 0; t < 4; ++t) {
            const int rl = t * 16 + lr;
#pragma unroll
            for (int i = 0; i < 4; ++i)
                cst[rl][cl + i] = acc[t][i] + bv[i];
        }
    }
    __syncthreads();

    // store sweep: one 1024-B contiguous wave store per node row chunk
    const int colbase = blockIdx.x * 256;
    const int c = lane * 4;                            // local col (f32)
#pragma unroll
    for (int r = 0; r < 16; ++r) {
        const int rl = w * 16 + r;
        const int node = r0 + rl;
        if (node < N_NODES && colbase + c < NL) {
            float4 o4;
            o4.x = cst[rl][c]; o4.y = cst[rl][c + 1];
            o4.z = cst[rl][c + 2]; o4.w = cst[rl][c + 3];
            *(float4*)(out + (size_t)node * NL + colbase + c) = o4;
        }
    }
}

// ---------------- launch ----------------

extern "C" void kernel_launch(void* const* d_in, const int* in_sizes, int n_in,
                              void* d_out, int out_size, void* d_ws, size_t ws_size,
                              hipStream_t stream) {
    const float* x      = (const float*)d_in[0];
    const int*   src    = (const int*)d_in[1];
    const int*   dst    = (const int*)d_in[2];
    const float* self_w = (const float*)d_in[3];
    const float* ppi_w  = (const float*)d_in[4];
    const float* W_in   = (const float*)d_in[5];
    const float* b_in   = (const float*)d_in[6];
    const float* W1     = (const float*)d_in[7];
    const float* b1     = (const float*)d_in[8];
    const float* W2     = (const float*)d_in[9];
    const float* b2     = (const float*)d_in[10];
    const float* W_out  = (const float*)d_in[11];
    const float* b_out  = (const float*)d_in[12];
    float* out = (float*)d_out;

    char* ws = (char*)d_ws;
    size_t o = 0;
    auto alloc = [&](size_t bytes) { void* p = ws + o; o += (bytes + 255) & ~(size_t)255; return p; };

    ushort_t* hb     = (ushort_t*)alloc((size_t)M_PAD * DH * 2);   // 12.8 MB
    ushort_t* hb2    = (ushort_t*)alloc((size_t)M_PAD * DH * 2);   // 12.8 MB
    int*      degz   = (int*)alloc((size_t)(N_NODES + 1) * 4);     // deg/cur + gcount
    int*      gcount = degz + N_NODES;
    int*      off_s  = (int*)alloc((size_t)N_NODES * 4);
    int*      off_pe = (int*)alloc((size_t)N_NODES * 4);
    int4*     er     = (int4*)alloc((size_t)E_PAD * 16);           // 16 MB records
    ushort_t* Bp_in  = (ushort_t*)alloc((size_t)T_IN * 8 * 2);
    ushort_t* Bp_1   = (ushort_t*)alloc((size_t)T_L * 8 * 2);
    ushort_t* Bp_2   = (ushort_t*)alloc((size_t)T_L * 8 * 2);
    ushort_t* Bp_out = (ushort_t*)alloc((size_t)T_OUT * 8 * 2);

    // CSR build: deg count (+ fused weight pack), wave-atomic alloc, scatter
    (void)hipMemsetAsync(degz, 0, (size_t)(N_NODES + 1) * 4, stream);
    count_pack_kernel<<<EB + PB, 256, 0, stream>>>(dst, degz, W_in, W1, W2, W_out,
                                                   Bp_in, Bp_1, Bp_2, Bp_out);
    alloc_kernel<<<(N_NODES + 255) / 256, 256, 0, stream>>>(degz, gcount, off_s, off_pe, er);
    scatter_kernel<<<EB, 256, 0, stream>>>(dst, src, self_w, ppi_w, off_s, degz, er);

    const dim3 g_h(1, M_PAD / 64);   // 782 blocks
    const dim3 g_o(4, M_PAD / 64);   // out GEMM: 4 x 256-label chunks

    // input linear: hb = relu(x @ W_in + b_in)
    mfma_in_kernel<<<g_h, 256, 0, stream>>>(x, Bp_in, b_in, hb);

    // layer 1 (fused aggregate + GEMM): hb2 = relu(agg @ W1 + b1) + res
    fused_layer_kernel<<<g_h, 256, 0, stream>>>(hb, off_s, off_pe, er, Bp_1, b1, hb2);

    // layer 2: hb = relu(agg @ W2 + b2) + res
    fused_layer_kernel<<<g_h, 256, 0, stream>>>(hb2, off_s, off_pe, er, Bp_2, b2, hb);

    // output linear: out = hb @ W_out + b_out  (LDS-staged contiguous stores)
    mfma_out_kernel<<<g_o, 256, 0, stream>>>(hb, Bp_out, b_out, out);
}

// Round 6
// 506.954 us; speedup vs baseline: 1.0815x; 1.0815x over previous
//
#include <hip/hip_runtime.h>

#define N_NODES 50000
#define M_PAD   50048          // nodes padded to multiple of 64
#define N_EDGES 800000
#define E_PAD   1000000        // >= N_EDGES + 3*N_NODES (4-padded segments)
#define DIN 256
#define DH  128
#define NL  1000
#define NL_PAD 1024

typedef unsigned short ushort_t;
typedef __attribute__((ext_vector_type(8))) short bf16x8;
typedef __attribute__((ext_vector_type(4))) float f32x4;
typedef __attribute__((ext_vector_type(4))) unsigned int u32x4;

__device__ __forceinline__ ushort_t f32_to_bf16_rne(float f) {
    unsigned int u = __float_as_uint(f);
    unsigned int r = (u + 0x7FFFu + ((u >> 16) & 1u)) >> 16;
    return (ushort_t)r;
}
// packs (lo,hi) f32 -> 2x bf16 in one instr (no builtin on gfx950; inline asm)
__device__ __forceinline__ unsigned cvt_pk_bf16(float lo, float hi) {
    unsigned r;
    asm("v_cvt_pk_bf16_f32 %0, %1, %2" : "=v"(r) : "v"(lo), "v"(hi));
    return r;
}
__device__ __forceinline__ float bf16_lo(unsigned u) { return __uint_as_float(u << 16); }
__device__ __forceinline__ float bf16_hi(unsigned u) { return __uint_as_float(u & 0xFFFF0000u); }

// ---------------- fused B-operand pack (fragment-contiguous) ----------------
__device__ __forceinline__ void pack_one(const float* __restrict__ W, ushort_t* __restrict__ Bp,
                                         int K, int Nreal, int t) {
    const int CHN = K / 32;
    int lane = t & 63;
    int c = (t >> 6) % CHN;
    int nt = (t >> 6) / CHN;
    int n = nt * 16 + (lane & 15);
    int kb = c * 32 + (lane >> 4) * 8;
    ushort_t* p = Bp + (size_t)t * 8;
#pragma unroll
    for (int j = 0; j < 8; ++j)
        p[j] = (n < Nreal) ? f32_to_bf16_rne(W[(size_t)(kb + j) * Nreal + n]) : (ushort_t)0;
}

#define T_IN  ((DH / 16) * (DIN / 32) * 64)        // 4096
#define T_L   ((DH / 16) * (DH / 32) * 64)         // 2048
#define T_OUT ((NL_PAD / 16) * (DH / 32) * 64)     // 16384
#define T_ALL (T_IN + 2 * T_L + T_OUT)             // 24576
#define EB    ((N_EDGES + 255) / 256)              // 3125
#define PB    (T_ALL / 256)                        // 96

// ---------------- CSR build ----------------

// blocks [0, EB): degree count + per-edge rank.  blocks [EB, EB+PB): weight pack.
__global__ void count_pack_kernel(const int* __restrict__ dst, int* __restrict__ deg,
                                  int* __restrict__ rank,
                                  const float* __restrict__ W_in, const float* __restrict__ W1,
                                  const float* __restrict__ W2, const float* __restrict__ W_out,
                                  ushort_t* __restrict__ Bp_in, ushort_t* __restrict__ Bp_1,
                                  ushort_t* __restrict__ Bp_2, ushort_t* __restrict__ Bp_out) {
    if (blockIdx.x < EB) {
        int e = blockIdx.x * blockDim.x + threadIdx.x;
        if (e < N_EDGES) rank[e] = atomicAdd(&deg[dst[e]], 1);
    } else {
        int tid = (blockIdx.x - EB) * blockDim.x + threadIdx.x;
        if (tid < T_IN) pack_one(W_in, Bp_in, DIN, DH, tid);
        else if (tid < T_IN + T_L) pack_one(W1, Bp_1, DH, DH, tid - T_IN);
        else if (tid < T_IN + 2 * T_L) pack_one(W2, Bp_2, DH, DH, tid - T_IN - T_L);
        else if (tid < T_ALL) pack_one(W_out, Bp_out, DH, NL, tid - T_IN - 2 * T_L);
    }
}

// Wave-atomic segment allocation: each node gets a 4-padded disjoint segment
// (order nondeterministic, contents deterministic). Zeroes only gap records.
__global__ __launch_bounds__(256) void alloc_kernel(
    const int* __restrict__ deg, int* __restrict__ gcount,
    int* __restrict__ off_s, int* __restrict__ off_pe,
    int4* __restrict__ er)
{
    const int node = blockIdx.x * blockDim.x + threadIdx.x;
    const int lane = threadIdx.x & 63;
    const bool ok = node < N_NODES;
    int d  = ok ? deg[node] : 0;
    int pd = (d + 3) & ~3;
    int pref = pd;
#pragma unroll
    for (int o = 1; o < 64; o <<= 1) {
        int v = __shfl_up(pref, o);
        if (lane >= o) pref += v;
    }
    int tot = __shfl(pref, 63);
    int base = 0;
    if (lane == 63) base = atomicAdd(gcount, tot);
    base = __shfl(base, 63);
    const int start = base + pref - pd;
    if (ok) {
        off_s[node]  = start;
        off_pe[node] = start + pd;
        for (int k = d; k < pd; ++k)          // zero gap records only
            er[start + k] = make_int4(0, 0, 0, 0);
    }
}

// Scatter edges into dst-sorted 16-B records using precomputed rank (no atomics).
__global__ void scatter_kernel(const int* __restrict__ dst, const int* __restrict__ src,
                               const float* __restrict__ self_w, const float* __restrict__ ppi_w,
                               const int* __restrict__ off_s, const int* __restrict__ rank,
                               int4* __restrict__ er) {
    int e = blockIdx.x * blockDim.x + threadIdx.x;
    if (e < N_EDGES) {
        int p = off_s[dst[e]] + rank[e];
        er[p] = make_int4(src[e], __float_as_int(ppi_w[e]), __float_as_int(self_w[e]), 0);
    }
}

// ---------------- input GEMM (reads f32 x, converts in-register) ------------
__global__ __launch_bounds__(256) void mfma_in_kernel(
    const float* __restrict__ x, const ushort_t* __restrict__ Bp,
    const float* __restrict__ bias, ushort_t* __restrict__ hb)
{
    constexpr int CHN = DIN / 32;                      // 8
    const int lane = threadIdx.x & 63;
    const int w    = threadIdx.x >> 6;
    const int r0   = blockIdx.y * 64;
    const int lr   = lane & 15;
    const int lq   = lane >> 4;

    bf16x8 bf[4][CHN];
#pragma unroll
    for (int t = 0; t < 4; ++t) {
        const int row = r0 + t * 16 + lr;
        const float* p = x + (size_t)row * DIN + lq * 8;
        const bool ok = row < N_NODES;
#pragma unroll
        for (int c = 0; c < CHN; ++c) {
            u32x4 uu = {0u, 0u, 0u, 0u};
            if (ok) {
                float4 f0 = ((const float4*)(p + c * 32))[0];
                float4 f1 = ((const float4*)(p + c * 32))[1];
                uu.x = cvt_pk_bf16(f0.x, f0.y);
                uu.y = cvt_pk_bf16(f0.z, f0.w);
                uu.z = cvt_pk_bf16(f1.x, f1.y);
                uu.w = cvt_pk_bf16(f1.z, f1.w);
            }
            bf[t][c] = __builtin_bit_cast(bf16x8, uu);
        }
    }

#pragma unroll
    for (int g = 0; g < 2; ++g) {
        const int dt = g * 4 + w;
        f32x4 acc[4] = {f32x4{0,0,0,0}, f32x4{0,0,0,0}, f32x4{0,0,0,0}, f32x4{0,0,0,0}};
#pragma unroll
        for (int c = 0; c < CHN; ++c) {
            bf16x8 afrag = *(const bf16x8*)(Bp + ((size_t)(dt * CHN + c) * 64 + lane) * 8);
#pragma unroll
            for (int t = 0; t < 4; ++t)
                acc[t] = __builtin_amdgcn_mfma_f32_16x16x32_bf16(afrag, bf[t][c], acc[t], 0, 0, 0);
        }
        const int d0 = dt * 16 + lq * 4;
        const float4 b4 = *(const float4*)(bias + d0);
#pragma unroll
        for (int t = 0; t < 4; ++t) {
            const int node = r0 + t * 16 + lr;
            float v[4];
            v[0] = fmaxf(acc[t][0] + b4.x, 0.f);
            v[1] = fmaxf(acc[t][1] + b4.y, 0.f);
            v[2] = fmaxf(acc[t][2] + b4.z, 0.f);
            v[3] = fmaxf(acc[t][3] + b4.w, 0.f);
            uint2 pp;
            pp.x = cvt_pk_bf16(v[0], v[1]);
            pp.y = cvt_pk_bf16(v[2], v[3]);
            *(uint2*)(hb + (size_t)node * DH + d0) = pp;
        }
    }
}

// ---------------- aggregation: quarter-wave, dwordx4 gathers ----------------
// 1 wave/node. 4 edges in flight per wave: quarter q (16 lanes) handles edge
// i+q with ONE dwordx4 gather per lane (16 B = 8 dims). 4x fewer VMEM
// instructions than the 4-B/lane version at identical in-flight bytes.
// Cross-quarter butterfly (xor 16/32) produces full sums in all lanes;
// quarter 0 stores agg row, quarter 1 stores res row (16-B packed stores).
__global__ __launch_bounds__(256) void aggregate_kernel(
    const ushort_t* __restrict__ hb,
    const int* __restrict__ off_s, const int* __restrict__ off_pe,
    const int4* __restrict__ er,
    ushort_t* __restrict__ agg_b, ushort_t* __restrict__ res_b)
{
    const int node = blockIdx.x * 4 + (threadIdx.x >> 6);
    const int lane = threadIdx.x & 63;
    const int q  = lane >> 4;
    const int li = lane & 15;
    float aa[8] = {0,0,0,0,0,0,0,0};
    float rr[8] = {0,0,0,0,0,0,0,0};
    if (node < N_NODES) {
        const int lo = off_s[node], hi = off_pe[node];
        int i = lo;
        for (; i + 8 <= hi; i += 8) {
            const int4 r0 = er[i + q];
            const int4 r1 = er[i + 4 + q];
            const u32x4 h0 = *(const u32x4*)(hb + (size_t)r0.x * DH + li * 8);
            const u32x4 h1 = *(const u32x4*)(hb + (size_t)r1.x * DH + li * 8);
            const float wp0 = __int_as_float(r0.y), ws0 = __int_as_float(r0.z);
            const float wp1 = __int_as_float(r1.y), ws1 = __int_as_float(r1.z);
#pragma unroll
            for (int d = 0; d < 4; ++d) {
                float l0 = bf16_lo(h0[d]), g0 = bf16_hi(h0[d]);
                float l1 = bf16_lo(h1[d]), g1 = bf16_hi(h1[d]);
                aa[2*d]   += wp0 * l0 + wp1 * l1;
                aa[2*d+1] += wp0 * g0 + wp1 * g1;
                rr[2*d]   += ws0 * l0 + ws1 * l1;
                rr[2*d+1] += ws0 * g0 + ws1 * g1;
            }
        }
        for (; i < hi; i += 4) {
            const int4 r0 = er[i + q];
            const u32x4 h0 = *(const u32x4*)(hb + (size_t)r0.x * DH + li * 8);
            const float wp0 = __int_as_float(r0.y), ws0 = __int_as_float(r0.z);
#pragma unroll
            for (int d = 0; d < 4; ++d) {
                float l0 = bf16_lo(h0[d]), g0 = bf16_hi(h0[d]);
                aa[2*d]   += wp0 * l0;
                aa[2*d+1] += wp0 * g0;
                rr[2*d]   += ws0 * l0;
                rr[2*d+1] += ws0 * g0;
            }
        }
    }
    // cross-quarter butterfly (uniform across wave; outside any divergence)
#pragma unroll
    for (int d = 0; d < 8; ++d) {
        aa[d] += __shfl_xor(aa[d], 16);
        aa[d] += __shfl_xor(aa[d], 32);
        rr[d] += __shfl_xor(rr[d], 16);
        rr[d] += __shfl_xor(rr[d], 32);
    }
    if (q == 0) {
        u32x4 pa;
        pa.x = cvt_pk_bf16(aa[0], aa[1]); pa.y = cvt_pk_bf16(aa[2], aa[3]);
        pa.z = cvt_pk_bf16(aa[4], aa[5]); pa.w = cvt_pk_bf16(aa[6], aa[7]);
        *(u32x4*)(agg_b + (size_t)node * DH + li * 8) = pa;
    } else if (q == 1) {
        u32x4 pr;
        pr.x = cvt_pk_bf16(rr[0], rr[1]); pr.y = cvt_pk_bf16(rr[2], rr[3]);
        pr.z = cvt_pk_bf16(rr[4], rr[5]); pr.w = cvt_pk_bf16(rr[6], rr[7]);
        *(u32x4*)(res_b + (size_t)node * DH + li * 8) = pr;
    }
}

// ---------------- hidden GEMM (bf16 in, bf16 out, bias+relu+res) ------------
__global__ __launch_bounds__(256) void mfma_hidden_kernel(
    const ushort_t* __restrict__ agg_b, const ushort_t* __restrict__ Bp,
    const float* __restrict__ bias, const ushort_t* __restrict__ res_b,
    ushort_t* __restrict__ hb_out)
{
    constexpr int CHN = DH / 32;                       // 4
    const int lane = threadIdx.x & 63;
    const int w    = threadIdx.x >> 6;
    const int r0   = blockIdx.y * 64;
    const int lr   = lane & 15;
    const int lq   = lane >> 4;

    bf16x8 bf[4][CHN];
#pragma unroll
    for (int t = 0; t < 4; ++t) {
        const ushort_t* p = agg_b + (size_t)(r0 + t * 16 + lr) * DH + lq * 8;
#pragma unroll
        for (int c = 0; c < CHN; ++c)
            bf[t][c] = *(const bf16x8*)(p + c * 32);
    }

#pragma unroll
    for (int g = 0; g < 2; ++g) {
        const int dt = g * 4 + w;
        f32x4 acc[4] = {f32x4{0,0,0,0}, f32x4{0,0,0,0}, f32x4{0,0,0,0}, f32x4{0,0,0,0}};
#pragma unroll
        for (int c = 0; c < CHN; ++c) {
            bf16x8 afrag = *(const bf16x8*)(Bp + ((size_t)(dt * CHN + c) * 64 + lane) * 8);
#pragma unroll
            for (int t = 0; t < 4; ++t)
                acc[t] = __builtin_amdgcn_mfma_f32_16x16x32_bf16(afrag, bf[t][c], acc[t], 0, 0, 0);
        }
        const int d0 = dt * 16 + lq * 4;
        const float4 b4 = *(const float4*)(bias + d0);
#pragma unroll
        for (int t = 0; t < 4; ++t) {
            const int node = r0 + t * 16 + lr;
            float v[4];
            v[0] = fmaxf(acc[t][0] + b4.x, 0.f);
            v[1] = fmaxf(acc[t][1] + b4.y, 0.f);
            v[2] = fmaxf(acc[t][2] + b4.z, 0.f);
            v[3] = fmaxf(acc[t][3] + b4.w, 0.f);
            const uint2 rw = *(const uint2*)(res_b + (size_t)node * DH + d0);
            v[0] += bf16_lo(rw.x); v[1] += bf16_hi(rw.x);
            v[2] += bf16_lo(rw.y); v[3] += bf16_hi(rw.y);
            uint2 pp;
            pp.x = cvt_pk_bf16(v[0], v[1]);
            pp.y = cvt_pk_bf16(v[2], v[3]);
            *(uint2*)(hb_out + (size_t)node * DH + d0) = pp;
        }
    }
}

// ---------------- output GEMM, 32-node blocks, LDS-staged stores ------------
// 33 KB LDS -> 4 blocks/CU (16 waves) for better store-latency overlap.
__global__ __launch_bounds__(256) void mfma_out_kernel(
    const ushort_t* __restrict__ hb, const ushort_t* __restrict__ Bp,
    const float* __restrict__ bias, float* __restrict__ out)
{
    constexpr int CHN = DH / 32;                       // 4
    __shared__ float cst[32][260];                     // 33.3 KB
    const int lane = threadIdx.x & 63;
    const int w    = threadIdx.x >> 6;
    const int r0   = blockIdx.y * 32;
    const int lr   = lane & 15;
    const int lq   = lane >> 4;

    bf16x8 bf[2][CHN];
#pragma unroll
    for (int t = 0; t < 2; ++t) {
        const ushort_t* p = hb + (size_t)(r0 + t * 16 + lr) * DH + lq * 8;
#pragma unroll
        for (int c = 0; c < CHN; ++c)
            bf[t][c] = *(const bf16x8*)(p + c * 32);
    }

#pragma unroll
    for (int g = 0; g < 4; ++g) {
        const int dt = (blockIdx.x * 4 + g) * 4 + w;   // global 16-label tile
        f32x4 acc[2] = {f32x4{0,0,0,0}, f32x4{0,0,0,0}};
#pragma unroll
        for (int c = 0; c < CHN; ++c) {
            bf16x8 afrag = *(const bf16x8*)(Bp + ((size_t)(dt * CHN + c) * 64 + lane) * 8);
#pragma unroll
            for (int t = 0; t < 2; ++t)
                acc[t] = __builtin_amdgcn_mfma_f32_16x16x32_bf16(afrag, bf[t][c], acc[t], 0, 0, 0);
        }

        const int d0 = dt * 16 + lq * 4;               // global label index
        float bv[4];
        if (d0 + 3 < NL) {
            const float4 b4 = *(const float4*)(bias + d0);
            bv[0] = b4.x; bv[1] = b4.y; bv[2] = b4.z; bv[3] = b4.w;
        } else {
#pragma unroll
            for (int i = 0; i < 4; ++i) bv[i] = (d0 + i < NL) ? bias[d0 + i] : 0.f;
        }
        const int cl = ((g * 4 + w) * 16) + lq * 4;    // local col in the 256-wide tile
#pragma unroll
        for (int t = 0; t < 2; ++t) {
            const int rl = t * 16 + lr;
#pragma unroll
            for (int i = 0; i < 4; ++i)
                cst[rl][cl + i] = acc[t][i] + bv[i];
        }
    }
    __syncthreads();

    // store sweep: one 1024-B contiguous wave store per node row chunk
    const int colbase = blockIdx.x * 256;
    const int c = lane * 4;                            // local col (f32)
#pragma unroll
    for (int r = 0; r < 8; ++r) {
        const int rl = w * 8 + r;
        const int node = r0 + rl;
        if (node < N_NODES && colbase + c < NL) {
            float4 o4;
            o4.x = cst[rl][c]; o4.y = cst[rl][c + 1];
            o4.z = cst[rl][c + 2]; o4.w = cst[rl][c + 3];
            *(float4*)(out + (size_t)node * NL + colbase + c) = o4;
        }
    }
}

// ---------------- launch ----------------

extern "C" void kernel_launch(void* const* d_in, const int* in_sizes, int n_in,
                              void* d_out, int out_size, void* d_ws, size_t ws_size,
                              hipStream_t stream) {
    const float* x      = (const float*)d_in[0];
    const int*   src    = (const int*)d_in[1];
    const int*   dst    = (const int*)d_in[2];
    const float* self_w = (const float*)d_in[3];
    const float* ppi_w  = (const float*)d_in[4];
    const float* W_in   = (const float*)d_in[5];
    const float* b_in   = (const float*)d_in[6];
    const float* W1     = (const float*)d_in[7];
    const float* b1     = (const float*)d_in[8];
    const float* W2     = (const float*)d_in[9];
    const float* b2     = (const float*)d_in[10];
    const float* W_out  = (const float*)d_in[11];
    const float* b_out  = (const float*)d_in[12];
    float* out = (float*)d_out;

    char* ws = (char*)d_ws;
    size_t o = 0;
    auto alloc = [&](size_t bytes) { void* p = ws + o; o += (bytes + 255) & ~(size_t)255; return p; };

    ushort_t* hb     = (ushort_t*)alloc((size_t)M_PAD * DH * 2);   // 12.8 MB
    ushort_t* hb2    = (ushort_t*)alloc((size_t)M_PAD * DH * 2);   // 12.8 MB
    ushort_t* agg_b  = (ushort_t*)alloc((size_t)M_PAD * DH * 2);   // 12.8 MB
    ushort_t* res_b  = (ushort_t*)alloc((size_t)M_PAD * DH * 2);   // 12.8 MB
    int*      degz   = (int*)alloc((size_t)(N_NODES + 1) * 4);     // deg + gcount
    int*      gcount = degz + N_NODES;
    int*      off_s  = (int*)alloc((size_t)N_NODES * 4);
    int*      off_pe = (int*)alloc((size_t)N_NODES * 4);
    int*      rank   = (int*)alloc((size_t)N_EDGES * 4);           // 3.2 MB
    int4*     er     = (int4*)alloc((size_t)E_PAD * 16);           // 16 MB records
    ushort_t* Bp_in  = (ushort_t*)alloc((size_t)T_IN * 8 * 2);
    ushort_t* Bp_1   = (ushort_t*)alloc((size_t)T_L * 8 * 2);
    ushort_t* Bp_2   = (ushort_t*)alloc((size_t)T_L * 8 * 2);
    ushort_t* Bp_out = (ushort_t*)alloc((size_t)T_OUT * 8 * 2);

    // CSR build: deg+rank count (+ fused weight pack), wave-atomic alloc, scatter
    (void)hipMemsetAsync(degz, 0, (size_t)(N_NODES + 1) * 4, stream);
    count_pack_kernel<<<EB + PB, 256, 0, stream>>>(dst, degz, rank, W_in, W1, W2, W_out,
                                                   Bp_in, Bp_1, Bp_2, Bp_out);
    alloc_kernel<<<(N_NODES + 255) / 256, 256, 0, stream>>>(degz, gcount, off_s, off_pe, er);
    scatter_kernel<<<EB, 256, 0, stream>>>(dst, src, self_w, ppi_w, off_s, rank, er);

    const dim3 g_h(1, M_PAD / 64);   // 782 blocks
    const dim3 g_o(4, M_PAD / 32);   // out GEMM: 4 x 256-label chunks, 32-node rows

    // input linear: hb = relu(x @ W_in + b_in)
    mfma_in_kernel<<<g_h, 256, 0, stream>>>(x, Bp_in, b_in, hb);

    // layer 1
    aggregate_kernel<<<M_PAD / 4, 256, 0, stream>>>(hb, off_s, off_pe, er, agg_b, res_b);
    mfma_hidden_kernel<<<g_h, 256, 0, stream>>>(agg_b, Bp_1, b1, res_b, hb2);

    // layer 2
    aggregate_kernel<<<M_PAD / 4, 256, 0, stream>>>(hb2, off_s, off_pe, er, agg_b, res_b);
    mfma_hidden_kernel<<<g_h, 256, 0, stream>>>(agg_b, Bp_2, b2, res_b, hb);

    // output linear: out = hb @ W_out + b_out  (LDS-staged contiguous stores)
    mfma_out_kernel<<<g_o, 256, 0, stream>>>(hb, Bp_out, b_out, out);
}

// Round 8
// 500.997 us; speedup vs baseline: 1.0943x; 1.0119x over previous
//
#include <hip/hip_runtime.h>

#define N_NODES 50000
#define M_PAD   50048          // nodes padded to multiple of 64
#define N_EDGES 800000
#define E_PAD   1000000        // >= max padded total (950K) + prefetch slack
#define DIN 256
#define DH  128
#define NL  1000
#define NL_PAD 1024

typedef unsigned short ushort_t;
typedef __attribute__((ext_vector_type(8))) short bf16x8;
typedef __attribute__((ext_vector_type(4))) float f32x4;
typedef __attribute__((ext_vector_type(4))) unsigned int u32x4;

__device__ __forceinline__ ushort_t f32_to_bf16_rne(float f) {
    unsigned int u = __float_as_uint(f);
    unsigned int r = (u + 0x7FFFu + ((u >> 16) & 1u)) >> 16;
    return (ushort_t)r;
}
// packs (lo,hi) f32 -> 2x bf16 in one instr (no builtin on gfx950; inline asm)
__device__ __forceinline__ unsigned cvt_pk_bf16(float lo, float hi) {
    unsigned r;
    asm("v_cvt_pk_bf16_f32 %0, %1, %2" : "=v"(r) : "v"(lo), "v"(hi));
    return r;
}
__device__ __forceinline__ float bf16_lo(unsigned u) { return __uint_as_float(u << 16); }
__device__ __forceinline__ float bf16_hi(unsigned u) { return __uint_as_float(u & 0xFFFF0000u); }

// ---------------- fused B-operand pack (fragment-contiguous) ----------------
__device__ __forceinline__ void pack_one(const float* __restrict__ W, ushort_t* __restrict__ Bp,
                                         int K, int Nreal, int t) {
    const int CHN = K / 32;
    int lane = t & 63;
    int c = (t >> 6) % CHN;
    int nt = (t >> 6) / CHN;
    int n = nt * 16 + (lane & 15);
    int kb = c * 32 + (lane >> 4) * 8;
    ushort_t* p = Bp + (size_t)t * 8;
#pragma unroll
    for (int j = 0; j < 8; ++j)
        p[j] = (n < Nreal) ? f32_to_bf16_rne(W[(size_t)(kb + j) * Nreal + n]) : (ushort_t)0;
}

#define T_IN  ((DH / 16) * (DIN / 32) * 64)        // 4096
#define T_L   ((DH / 16) * (DH / 32) * 64)         // 2048
#define T_OUT ((NL_PAD / 16) * (DH / 32) * 64)     // 16384
#define T_ALL (T_IN + 2 * T_L + T_OUT)             // 24576
#define EB    ((N_EDGES + 255) / 256)              // 3125
#define PB    (T_ALL / 256)                        // 96
#define MB_IN (M_PAD / 64)                         // 782

// ---------------- CSR build ----------------

// blocks [0, EB): degree count + per-edge rank.  blocks [EB, EB+PB): weight pack.
__global__ void count_pack_kernel(const int* __restrict__ dst, int* __restrict__ deg,
                                  int* __restrict__ rank,
                                  const float* __restrict__ W_in, const float* __restrict__ W1,
                                  const float* __restrict__ W2, const float* __restrict__ W_out,
                                  ushort_t* __restrict__ Bp_in, ushort_t* __restrict__ Bp_1,
                                  ushort_t* __restrict__ Bp_2, ushort_t* __restrict__ Bp_out) {
    if (blockIdx.x < EB) {
        int e = blockIdx.x * blockDim.x + threadIdx.x;
        if (e < N_EDGES) rank[e] = atomicAdd(&deg[dst[e]], 1);
    } else {
        int tid = (blockIdx.x - EB) * blockDim.x + threadIdx.x;
        if (tid < T_IN) pack_one(W_in, Bp_in, DIN, DH, tid);
        else if (tid < T_IN + T_L) pack_one(W1, Bp_1, DH, DH, tid - T_IN);
        else if (tid < T_IN + 2 * T_L) pack_one(W2, Bp_2, DH, DH, tid - T_IN - T_L);
        else if (tid < T_ALL) pack_one(W_out, Bp_out, DH, NL, tid - T_IN - 2 * T_L);
    }
}

// Wave-atomic segment allocation: each node gets a 4-padded disjoint segment
// (order nondeterministic, contents deterministic). Zeroes only gap records.
__global__ __launch_bounds__(256) void alloc_kernel(
    const int* __restrict__ deg, int* __restrict__ gcount,
    int* __restrict__ off_s, int* __restrict__ off_pe,
    int4* __restrict__ er)
{
    const int node = blockIdx.x * blockDim.x + threadIdx.x;
    const int lane = threadIdx.x & 63;
    const bool ok = node < N_NODES;
    int d  = ok ? deg[node] : 0;
    int pd = (d + 3) & ~3;
    int pref = pd;
#pragma unroll
    for (int o = 1; o < 64; o <<= 1) {
        int v = __shfl_up(pref, o);
        if (lane >= o) pref += v;
    }
    int tot = __shfl(pref, 63);
    int base = 0;
    if (lane == 63) base = atomicAdd(gcount, tot);
    base = __shfl(base, 63);
    const int start = base + pref - pd;
    if (ok) {
        off_s[node]  = start;
        off_pe[node] = start + pd;
        for (int k = d; k < pd; ++k)          // zero gap records only
            er[start + k] = make_int4(0, 0, 0, 0);
    }
}

// ---------------- fused: scatter + input GEMM ----------------
// blocks [0, EB): scatter edges into dst-sorted 16-B records (rank-based, no
// atomics).  blocks [EB, EB+MB_IN): input GEMM (independent of CSR) — its
// read-BW + MFMA work overlaps the latency-bound random scatter stores.
__device__ __forceinline__ void scatter_body(
    const int* __restrict__ dst, const int* __restrict__ src,
    const float* __restrict__ self_w, const float* __restrict__ ppi_w,
    const int* __restrict__ off_s, const int* __restrict__ rank,
    int4* __restrict__ er)
{
    int e = blockIdx.x * blockDim.x + threadIdx.x;
    if (e < N_EDGES) {
        int p = off_s[dst[e]] + rank[e];
        er[p] = make_int4(src[e], __float_as_int(ppi_w[e]), __float_as_int(self_w[e]), 0);
    }
}

__device__ __forceinline__ void mfma_in_body(
    const float* __restrict__ x, const ushort_t* __restrict__ Bp,
    const float* __restrict__ bias, ushort_t* __restrict__ hb, int bx)
{
    constexpr int CHN = DIN / 32;                      // 8
    const int lane = threadIdx.x & 63;
    const int w    = threadIdx.x >> 6;
    const int r0   = bx * 64;
    const int lr   = lane & 15;
    const int lq   = lane >> 4;

    bf16x8 bf[4][CHN];
#pragma unroll
    for (int t = 0; t < 4; ++t) {
        const int row = r0 + t * 16 + lr;
        const float* p = x + (size_t)row * DIN + lq * 8;
        const bool ok = row < N_NODES;
#pragma unroll
        for (int c = 0; c < CHN; ++c) {
            u32x4 uu = {0u, 0u, 0u, 0u};
            if (ok) {
                float4 f0 = ((const float4*)(p + c * 32))[0];
                float4 f1 = ((const float4*)(p + c * 32))[1];
                uu.x = cvt_pk_bf16(f0.x, f0.y);
                uu.y = cvt_pk_bf16(f0.z, f0.w);
                uu.z = cvt_pk_bf16(f1.x, f1.y);
                uu.w = cvt_pk_bf16(f1.z, f1.w);
            }
            bf[t][c] = __builtin_bit_cast(bf16x8, uu);
        }
    }

#pragma unroll
    for (int g = 0; g < 2; ++g) {
        const int dt = g * 4 + w;
        f32x4 acc[4] = {f32x4{0,0,0,0}, f32x4{0,0,0,0}, f32x4{0,0,0,0}, f32x4{0,0,0,0}};
#pragma unroll
        for (int c = 0; c < CHN; ++c) {
            bf16x8 afrag = *(const bf16x8*)(Bp + ((size_t)(dt * CHN + c) * 64 + lane) * 8);
#pragma unroll
            for (int t = 0; t < 4; ++t)
                acc[t] = __builtin_amdgcn_mfma_f32_16x16x32_bf16(afrag, bf[t][c], acc[t], 0, 0, 0);
        }
        const int d0 = dt * 16 + lq * 4;
        const float4 b4 = *(const float4*)(bias + d0);
#pragma unroll
        for (int t = 0; t < 4; ++t) {
            const int node = r0 + t * 16 + lr;
            float v[4];
            v[0] = fmaxf(acc[t][0] + b4.x, 0.f);
            v[1] = fmaxf(acc[t][1] + b4.y, 0.f);
            v[2] = fmaxf(acc[t][2] + b4.z, 0.f);
            v[3] = fmaxf(acc[t][3] + b4.w, 0.f);
            uint2 pp;
            pp.x = cvt_pk_bf16(v[0], v[1]);
            pp.y = cvt_pk_bf16(v[2], v[3]);
            *(uint2*)(hb + (size_t)node * DH + d0) = pp;
        }
    }
}

__global__ __launch_bounds__(256) void scatter_in_kernel(
    const int* __restrict__ dst, const int* __restrict__ src,
    const float* __restrict__ self_w, const float* __restrict__ ppi_w,
    const int* __restrict__ off_s, const int* __restrict__ rank,
    int4* __restrict__ er,
    const float* __restrict__ x, const ushort_t* __restrict__ Bp_in,
    const float* __restrict__ b_in, ushort_t* __restrict__ hb)
{
    if (blockIdx.x < EB)
        scatter_body(dst, src, self_w, ppi_w, off_s, rank, er);
    else
        mfma_in_body(x, Bp_in, b_in, hb, blockIdx.x - EB);
}

// ---------------- aggregation: quarter-wave dwordx4 gathers, rec prefetch ---
// 1 wave/node; quarter q handles edge i+q with one dwordx4 gather per lane.
// Next iteration's records prefetched before current gathers (breaks the
// rec->gather serial chain). Prefetch reads stay within E_PAD slack.
__global__ __launch_bounds__(256) void aggregate_kernel(
    const ushort_t* __restrict__ hb,
    const int* __restrict__ off_s, const int* __restrict__ off_pe,
    const int4* __restrict__ er,
    ushort_t* __restrict__ agg_b, ushort_t* __restrict__ res_b)
{
    const int node = blockIdx.x * 4 + (threadIdx.x >> 6);
    const int lane = threadIdx.x & 63;
    const int q  = lane >> 4;
    const int li = lane & 15;
    float aa[8] = {0,0,0,0,0,0,0,0};
    float rr[8] = {0,0,0,0,0,0,0,0};
    if (node < N_NODES) {
        const int lo = off_s[node], hi = off_pe[node];
        int i = lo;
        if (i + 8 <= hi) {
            int4 c0 = er[i + q];
            int4 c1 = er[i + 4 + q];
            for (; i + 8 <= hi; i += 8) {
                // prefetch next iteration's records (unconditional; slack-safe)
                const int4 n0 = er[i + 8 + q];
                const int4 n1 = er[i + 12 + q];
                const u32x4 h0 = *(const u32x4*)(hb + (size_t)c0.x * DH + li * 8);
                const u32x4 h1 = *(const u32x4*)(hb + (size_t)c1.x * DH + li * 8);
                const float wp0 = __int_as_float(c0.y), ws0 = __int_as_float(c0.z);
                const float wp1 = __int_as_float(c1.y), ws1 = __int_as_float(c1.z);
#pragma unroll
                for (int d = 0; d < 4; ++d) {
                    float l0 = bf16_lo(h0[d]), g0 = bf16_hi(h0[d]);
                    float l1 = bf16_lo(h1[d]), g1 = bf16_hi(h1[d]);
                    aa[2*d]   += wp0 * l0 + wp1 * l1;
                    aa[2*d+1] += wp0 * g0 + wp1 * g1;
                    rr[2*d]   += ws0 * l0 + ws1 * l1;
                    rr[2*d+1] += ws0 * g0 + ws1 * g1;
                }
                c0 = n0; c1 = n1;
            }
        }
        for (; i < hi; i += 4) {
            const int4 r0 = er[i + q];
            const u32x4 h0 = *(const u32x4*)(hb + (size_t)r0.x * DH + li * 8);
            const float wp0 = __int_as_float(r0.y), ws0 = __int_as_float(r0.z);
#pragma unroll
            for (int d = 0; d < 4; ++d) {
                float l0 = bf16_lo(h0[d]), g0 = bf16_hi(h0[d]);
                aa[2*d]   += wp0 * l0;
                aa[2*d+1] += wp0 * g0;
                rr[2*d]   += ws0 * l0;
                rr[2*d+1] += ws0 * g0;
            }
        }
    }
    // cross-quarter butterfly (uniform across wave; outside any divergence)
#pragma unroll
    for (int d = 0; d < 8; ++d) {
        aa[d] += __shfl_xor(aa[d], 16);
        aa[d] += __shfl_xor(aa[d], 32);
        rr[d] += __shfl_xor(rr[d], 16);
        rr[d] += __shfl_xor(rr[d], 32);
    }
    if (q == 0) {
        u32x4 pa;
        pa.x = cvt_pk_bf16(aa[0], aa[1]); pa.y = cvt_pk_bf16(aa[2], aa[3]);
        pa.z = cvt_pk_bf16(aa[4], aa[5]); pa.w = cvt_pk_bf16(aa[6], aa[7]);
        *(u32x4*)(agg_b + (size_t)node * DH + li * 8) = pa;
    } else if (q == 1) {
        u32x4 pr;
        pr.x = cvt_pk_bf16(rr[0], rr[1]); pr.y = cvt_pk_bf16(rr[2], rr[3]);
        pr.z = cvt_pk_bf16(rr[4], rr[5]); pr.w = cvt_pk_bf16(rr[6], rr[7]);
        *(u32x4*)(res_b + (size_t)node * DH + li * 8) = pr;
    }
}

// ---------------- hidden GEMM (bf16 in, bf16 out, bias+relu+res) ------------
__global__ __launch_bounds__(256) void mfma_hidden_kernel(
    const ushort_t* __restrict__ agg_b, const ushort_t* __restrict__ Bp,
    const float* __restrict__ bias, const ushort_t* __restrict__ res_b,
    ushort_t* __restrict__ hb_out)
{
    constexpr int CHN = DH / 32;                       // 4
    const int lane = threadIdx.x & 63;
    const int w    = threadIdx.x >> 6;
    const int r0   = blockIdx.y * 64;
    const int lr   = lane & 15;
    const int lq   = lane >> 4;

    bf16x8 bf[4][CHN];
#pragma unroll
    for (int t = 0; t < 4; ++t) {
        const ushort_t* p = agg_b + (size_t)(r0 + t * 16 + lr) * DH + lq * 8;
#pragma unroll
        for (int c = 0; c < CHN; ++c)
            bf[t][c] = *(const bf16x8*)(p + c * 32);
    }

#pragma unroll
    for (int g = 0; g < 2; ++g) {
        const int dt = g * 4 + w;
        f32x4 acc[4] = {f32x4{0,0,0,0}, f32x4{0,0,0,0}, f32x4{0,0,0,0}, f32x4{0,0,0,0}};
#pragma unroll
        for (int c = 0; c < CHN; ++c) {
            bf16x8 afrag = *(const bf16x8*)(Bp + ((size_t)(dt * CHN + c) * 64 + lane) * 8);
#pragma unroll
            for (int t = 0; t < 4; ++t)
                acc[t] = __builtin_amdgcn_mfma_f32_16x16x32_bf16(afrag, bf[t][c], acc[t], 0, 0, 0);
        }
        const int d0 = dt * 16 + lq * 4;
        const float4 b4 = *(const float4*)(bias + d0);
#pragma unroll
        for (int t = 0; t < 4; ++t) {
            const int node = r0 + t * 16 + lr;
            float v[4];
            v[0] = fmaxf(acc[t][0] + b4.x, 0.f);
            v[1] = fmaxf(acc[t][1] + b4.y, 0.f);
            v[2] = fmaxf(acc[t][2] + b4.z, 0.f);
            v[3] = fmaxf(acc[t][3] + b4.w, 0.f);
            const uint2 rw = *(const uint2*)(res_b + (size_t)node * DH + d0);
            v[0] += bf16_lo(rw.x); v[1] += bf16_hi(rw.x);
            v[2] += bf16_lo(rw.y); v[3] += bf16_hi(rw.y);
            uint2 pp;
            pp.x = cvt_pk_bf16(v[0], v[1]);
            pp.y = cvt_pk_bf16(v[2], v[3]);
            *(uint2*)(hb_out + (size_t)node * DH + d0) = pp;
        }
    }
}

// ---------------- output GEMM, 32-node blocks, LDS-staged stores ------------
__global__ __launch_bounds__(256) void mfma_out_kernel(
    const ushort_t* __restrict__ hb, const ushort_t* __restrict__ Bp,
    const float* __restrict__ bias, float* __restrict__ out)
{
    constexpr int CHN = DH / 32;                       // 4
    __shared__ float cst[32][260];                     // 33.3 KB
    const int lane = threadIdx.x & 63;
    const int w    = threadIdx.x >> 6;
    const int r0   = blockIdx.y * 32;
    const int lr   = lane & 15;
    const int lq   = lane >> 4;

    bf16x8 bf[2][CHN];
#pragma unroll
    for (int t = 0; t < 2; ++t) {
        const ushort_t* p = hb + (size_t)(r0 + t * 16 + lr) * DH + lq * 8;
#pragma unroll
        for (int c = 0; c < CHN; ++c)
            bf[t][c] = *(const bf16x8*)(p + c * 32);
    }

#pragma unroll
    for (int g = 0; g < 4; ++g) {
        const int dt = (blockIdx.x * 4 + g) * 4 + w;   // global 16-label tile
        f32x4 acc[2] = {f32x4{0,0,0,0}, f32x4{0,0,0,0}};
#pragma unroll
        for (int c = 0; c < CHN; ++c) {
            bf16x8 afrag = *(const bf16x8*)(Bp + ((size_t)(dt * CHN + c) * 64 + lane) * 8);
#pragma unroll
            for (int t = 0; t < 2; ++t)
                acc[t] = __builtin_amdgcn_mfma_f32_16x16x32_bf16(afrag, bf[t][c], acc[t], 0, 0, 0);
        }

        const int d0 = dt * 16 + lq * 4;               // global label index
        float bv[4];
        if (d0 + 3 < NL) {
            const float4 b4 = *(const float4*)(bias + d0);
            bv[0] = b4.x; bv[1] = b4.y; bv[2] = b4.z; bv[3] = b4.w;
        } else {
#pragma unroll
            for (int i = 0; i < 4; ++i) bv[i] = (d0 + i < NL) ? bias[d0 + i] : 0.f;
        }
        const int cl = ((g * 4 + w) * 16) + lq * 4;    // local col in the 256-wide tile
#pragma unroll
        for (int t = 0; t < 2; ++t) {
            const int rl = t * 16 + lr;
#pragma unroll
            for (int i = 0; i < 4; ++i)
                cst[rl][cl + i] = acc[t][i] + bv[i];
        }
    }
    __syncthreads();

    // store sweep: one 1024-B contiguous wave store per node row chunk
    const int colbase = blockIdx.x * 256;
    const int c = lane * 4;                            // local col (f32)
#pragma unroll
    for (int r = 0; r < 8; ++r) {
        const int rl = w * 8 + r;
        const int node = r0 + rl;
        if (node < N_NODES && colbase + c < NL) {
            float4 o4;
            o4.x = cst[rl][c]; o4.y = cst[rl][c + 1];
            o4.z = cst[rl][c + 2]; o4.w = cst[rl][c + 3];
            *(float4*)(out + (size_t)node * NL + colbase + c) = o4;
        }
    }
}

// ---------------- launch ----------------

extern "C" void kernel_launch(void* const* d_in, const int* in_sizes, int n_in,
                              void* d_out, int out_size, void* d_ws, size_t ws_size,
                              hipStream_t stream) {
    const float* x      = (const float*)d_in[0];
    const int*   src    = (const int*)d_in[1];
    const int*   dst    = (const int*)d_in[2];
    const float* self_w = (const float*)d_in[3];
    const float* ppi_w  = (const float*)d_in[4];
    const float* W_in   = (const float*)d_in[5];
    const float* b_in   = (const float*)d_in[6];
    const float* W1     = (const float*)d_in[7];
    const float* b1     = (const float*)d_in[8];
    const float* W2     = (const float*)d_in[9];
    const float* b2     = (const float*)d_in[10];
    const float* W_out  = (const float*)d_in[11];
    const float* b_out  = (const float*)d_in[12];
    float* out = (float*)d_out;

    char* ws = (char*)d_ws;
    size_t o = 0;
    auto alloc = [&](size_t bytes) { void* p = ws + o; o += (bytes + 255) & ~(size_t)255; return p; };

    ushort_t* hb     = (ushort_t*)alloc((size_t)M_PAD * DH * 2);   // 12.8 MB
    ushort_t* hb2    = (ushort_t*)alloc((size_t)M_PAD * DH * 2);   // 12.8 MB
    ushort_t* agg_b  = (ushort_t*)alloc((size_t)M_PAD * DH * 2);   // 12.8 MB
    ushort_t* res_b  = (ushort_t*)alloc((size_t)M_PAD * DH * 2);   // 12.8 MB
    int*      degz   = (int*)alloc((size_t)(N_NODES + 1) * 4);     // deg + gcount
    int*      gcount = degz + N_NODES;
    int*      off_s  = (int*)alloc((size_t)N_NODES * 4);
    int*      off_pe = (int*)alloc((size_t)N_NODES * 4);
    int*      rank   = (int*)alloc((size_t)N_EDGES * 4);           // 3.2 MB
    int4*     er     = (int4*)alloc((size_t)E_PAD * 16);           // 16 MB records
    ushort_t* Bp_in  = (ushort_t*)alloc((size_t)T_IN * 8 * 2);
    ushort_t* Bp_1   = (ushort_t*)alloc((size_t)T_L * 8 * 2);
    ushort_t* Bp_2   = (ushort_t*)alloc((size_t)T_L * 8 * 2);
    ushort_t* Bp_out = (ushort_t*)alloc((size_t)T_OUT * 8 * 2);

    // CSR build: deg+rank count (+ fused weight pack), wave-atomic alloc
    (void)hipMemsetAsync(degz, 0, (size_t)(N_NODES + 1) * 4, stream);
    count_pack_kernel<<<EB + PB, 256, 0, stream>>>(dst, degz, rank, W_in, W1, W2, W_out,
                                                   Bp_in, Bp_1, Bp_2, Bp_out);
    alloc_kernel<<<(N_NODES + 255) / 256, 256, 0, stream>>>(degz, gcount, off_s, off_pe, er);

    // fused scatter + input GEMM (independent work overlapped in one dispatch)
    scatter_in_kernel<<<EB + MB_IN, 256, 0, stream>>>(dst, src, self_w, ppi_w, off_s, rank, er,
                                                      x, Bp_in, b_in, hb);

    const dim3 g_h(1, M_PAD / 64);   // 782 blocks
    const dim3 g_o(4, M_PAD / 32);   // out GEMM: 4 x 256-label chunks, 32-node rows

    // layer 1
    aggregate_kernel<<<M_PAD / 4, 256, 0, stream>>>(hb, off_s, off_pe, er, agg_b, res_b);
    mfma_hidden_kernel<<<g_h, 256, 0, stream>>>(agg_b, Bp_1, b1, res_b, hb2);

    // layer 2
    aggregate_kernel<<<M_PAD / 4, 256, 0, stream>>>(hb2, off_s, off_pe, er, agg_b, res_b);
    mfma_hidden_kernel<<<g_h, 256, 0, stream>>>(agg_b, Bp_2, b2, res_b, hb);

    // output linear: out = hb @ W_out + b_out  (LDS-staged contiguous stores)
    mfma_out_kernel<<<g_o, 256, 0, stream>>>(hb, Bp_out, b_out, out);
}

// Round 10
// 496.568 us; speedup vs baseline: 1.1041x; 1.0089x over previous
//
#include <hip/hip_runtime.h>

#define N_NODES 50000
#define M_PAD   50048          // nodes padded to multiple of 64
#define N_EDGES 800000
#define E_PAD   1000000        // >= max padded total (950K)
#define DIN 256
#define DH  128
#define NL  1000
#define NL_PAD 1024

typedef unsigned short ushort_t;
typedef __attribute__((ext_vector_type(8))) short bf16x8;
typedef __attribute__((ext_vector_type(4))) float f32x4;
typedef __attribute__((ext_vector_type(4))) unsigned int u32x4;

__device__ __forceinline__ ushort_t f32_to_bf16_rne(float f) {
    unsigned int u = __float_as_uint(f);
    unsigned int r = (u + 0x7FFFu + ((u >> 16) & 1u)) >> 16;
    return (ushort_t)r;
}
// packs (lo,hi) f32 -> 2x bf16 in one instr (no builtin on gfx950; inline asm)
__device__ __forceinline__ unsigned cvt_pk_bf16(float lo, float hi) {
    unsigned r;
    asm("v_cvt_pk_bf16_f32 %0, %1, %2" : "=v"(r) : "v"(lo), "v"(hi));
    return r;
}
__device__ __forceinline__ float bf16_lo(unsigned u) { return __uint_as_float(u << 16); }
__device__ __forceinline__ float bf16_hi(unsigned u) { return __uint_as_float(u & 0xFFFF0000u); }

// ---------------- fused B-operand pack (fragment-contiguous) ----------------
__device__ __forceinline__ void pack_one(const float* __restrict__ W, ushort_t* __restrict__ Bp,
                                         int K, int Nreal, int t) {
    const int CHN = K / 32;
    int lane = t & 63;
    int c = (t >> 6) % CHN;
    int nt = (t >> 6) / CHN;
    int n = nt * 16 + (lane & 15);
    int kb = c * 32 + (lane >> 4) * 8;
    ushort_t* p = Bp + (size_t)t * 8;
#pragma unroll
    for (int j = 0; j < 8; ++j)
        p[j] = (n < Nreal) ? f32_to_bf16_rne(W[(size_t)(kb + j) * Nreal + n]) : (ushort_t)0;
}

#define T_IN  ((DH / 16) * (DIN / 32) * 64)        // 4096
#define T_L   ((DH / 16) * (DH / 32) * 64)         // 2048
#define T_OUT ((NL_PAD / 16) * (DH / 32) * 64)     // 16384
#define T_ALL (T_IN + 2 * T_L + T_OUT)             // 24576
#define EB    ((N_EDGES + 255) / 256)              // 3125
#define PB    (T_ALL / 256)                        // 96
#define MB_IN (M_PAD / 64)                         // 782

// ---------------- CSR build ----------------

// blocks [0, EB): degree count + per-edge rank.  blocks [EB, EB+PB): weight pack.
__global__ void count_pack_kernel(const int* __restrict__ dst, int* __restrict__ deg,
                                  int* __restrict__ rank,
                                  const float* __restrict__ W_in, const float* __restrict__ W1,
                                  const float* __restrict__ W2, const float* __restrict__ W_out,
                                  ushort_t* __restrict__ Bp_in, ushort_t* __restrict__ Bp_1,
                                  ushort_t* __restrict__ Bp_2, ushort_t* __restrict__ Bp_out) {
    if (blockIdx.x < EB) {
        int e = blockIdx.x * blockDim.x + threadIdx.x;
        if (e < N_EDGES) rank[e] = atomicAdd(&deg[dst[e]], 1);
    } else {
        int tid = (blockIdx.x - EB) * blockDim.x + threadIdx.x;
        if (tid < T_IN) pack_one(W_in, Bp_in, DIN, DH, tid);
        else if (tid < T_IN + T_L) pack_one(W1, Bp_1, DH, DH, tid - T_IN);
        else if (tid < T_IN + 2 * T_L) pack_one(W2, Bp_2, DH, DH, tid - T_IN - T_L);
        else if (tid < T_ALL) pack_one(W_out, Bp_out, DH, NL, tid - T_IN - 2 * T_L);
    }
}

// Wave-atomic segment allocation: each node gets a 4-padded disjoint segment
// (order nondeterministic, contents deterministic). Zeroes only gap records.
__global__ __launch_bounds__(256) void alloc_kernel(
    const int* __restrict__ deg, int* __restrict__ gcount,
    int* __restrict__ off_s, int* __restrict__ off_pe,
    int4* __restrict__ er)
{
    const int node = blockIdx.x * blockDim.x + threadIdx.x;
    const int lane = threadIdx.x & 63;
    const bool ok = node < N_NODES;
    int d  = ok ? deg[node] : 0;
    int pd = (d + 3) & ~3;
    int pref = pd;
#pragma unroll
    for (int o = 1; o < 64; o <<= 1) {
        int v = __shfl_up(pref, o);
        if (lane >= o) pref += v;
    }
    int tot = __shfl(pref, 63);
    int base = 0;
    if (lane == 63) base = atomicAdd(gcount, tot);
    base = __shfl(base, 63);
    const int start = base + pref - pd;
    if (ok) {
        off_s[node]  = start;
        off_pe[node] = start + pd;
        for (int k = d; k < pd; ++k)          // zero gap records only
            er[start + k] = make_int4(0, 0, 0, 0);
    }
}

// ---------------- fused: scatter + input GEMM ----------------
__device__ __forceinline__ void scatter_body(
    const int* __restrict__ dst, const int* __restrict__ src,
    const float* __restrict__ self_w, const float* __restrict__ ppi_w,
    const int* __restrict__ off_s, const int* __restrict__ rank,
    int4* __restrict__ er)
{
    int e = blockIdx.x * blockDim.x + threadIdx.x;
    if (e < N_EDGES) {
        int p = off_s[dst[e]] + rank[e];
        er[p] = make_int4(src[e], __float_as_int(ppi_w[e]), __float_as_int(self_w[e]), 0);
    }
}

__device__ __forceinline__ void mfma_in_body(
    const float* __restrict__ x, const ushort_t* __restrict__ Bp,
    const float* __restrict__ bias, ushort_t* __restrict__ hb, int bx)
{
    constexpr int CHN = DIN / 32;                      // 8
    const int lane = threadIdx.x & 63;
    const int w    = threadIdx.x >> 6;
    const int r0   = bx * 64;
    const int lr   = lane & 15;
    const int lq   = lane >> 4;

    bf16x8 bf[4][CHN];
#pragma unroll
    for (int t = 0; t < 4; ++t) {
        const int row = r0 + t * 16 + lr;
        const float* p = x + (size_t)row * DIN + lq * 8;
        const bool ok = row < N_NODES;
#pragma unroll
        for (int c = 0; c < CHN; ++c) {
            u32x4 uu = {0u, 0u, 0u, 0u};
            if (ok) {
                float4 f0 = ((const float4*)(p + c * 32))[0];
                float4 f1 = ((const float4*)(p + c * 32))[1];
                uu.x = cvt_pk_bf16(f0.x, f0.y);
                uu.y = cvt_pk_bf16(f0.z, f0.w);
                uu.z = cvt_pk_bf16(f1.x, f1.y);
                uu.w = cvt_pk_bf16(f1.z, f1.w);
            }
            bf[t][c] = __builtin_bit_cast(bf16x8, uu);
        }
    }

#pragma unroll
    for (int g = 0; g < 2; ++g) {
        const int dt = g * 4 + w;
        f32x4 acc[4] = {f32x4{0,0,0,0}, f32x4{0,0,0,0}, f32x4{0,0,0,0}, f32x4{0,0,0,0}};
#pragma unroll
        for (int c = 0; c < CHN; ++c) {
            bf16x8 afrag = *(const bf16x8*)(Bp + ((size_t)(dt * CHN + c) * 64 + lane) * 8);
#pragma unroll
            for (int t = 0; t < 4; ++t)
                acc[t] = __builtin_amdgcn_mfma_f32_16x16x32_bf16(afrag, bf[t][c], acc[t], 0, 0, 0);
        }
        const int d0 = dt * 16 + lq * 4;
        const float4 b4 = *(const float4*)(bias + d0);
#pragma unroll
        for (int t = 0; t < 4; ++t) {
            const int node = r0 + t * 16 + lr;
            float v[4];
            v[0] = fmaxf(acc[t][0] + b4.x, 0.f);
            v[1] = fmaxf(acc[t][1] + b4.y, 0.f);
            v[2] = fmaxf(acc[t][2] + b4.z, 0.f);
            v[3] = fmaxf(acc[t][3] + b4.w, 0.f);
            uint2 pp;
            pp.x = cvt_pk_bf16(v[0], v[1]);
            pp.y = cvt_pk_bf16(v[2], v[3]);
            *(uint2*)(hb + (size_t)node * DH + d0) = pp;
        }
    }
}

__global__ __launch_bounds__(256) void scatter_in_kernel(
    const int* __restrict__ dst, const int* __restrict__ src,
    const float* __restrict__ self_w, const float* __restrict__ ppi_w,
    const int* __restrict__ off_s, const int* __restrict__ rank,
    int4* __restrict__ er,
    const float* __restrict__ x, const ushort_t* __restrict__ Bp_in,
    const float* __restrict__ b_in, ushort_t* __restrict__ hb)
{
    if (blockIdx.x < EB)
        scatter_body(dst, src, self_w, ppi_w, off_s, rank, er);
    else
        mfma_in_body(x, Bp_in, b_in, hb, blockIdx.x - EB);
}

// ---------------- aggregation: 16-edge batched quarter-wave gathers ---------
// 1 wave/node. Main body: quarter q handles edges i+4q..i+4q+3 — 4 record
// loads (quarter-broadcast) + 4 INDEPENDENT dwordx4 gathers per lane issued
// back-to-back -> 16 gathers in flight per wave (2x the 8-edge version).
// With deg~16-19 one main iteration covers nearly the whole node.
// All indices in-segment. 4-edge tail as before; cross-quarter butterfly.
__global__ __launch_bounds__(256) void aggregate_kernel(
    const ushort_t* __restrict__ hb,
    const int* __restrict__ off_s, const int* __restrict__ off_pe,
    const int4* __restrict__ er,
    ushort_t* __restrict__ agg_b, ushort_t* __restrict__ res_b)
{
    const int node = blockIdx.x * 4 + (threadIdx.x >> 6);
    const int lane = threadIdx.x & 63;
    const int q  = lane >> 4;
    const int li = lane & 15;
    float aa[8] = {0,0,0,0,0,0,0,0};
    float rr[8] = {0,0,0,0,0,0,0,0};
    if (node < N_NODES) {
        const int lo = off_s[node], hi = off_pe[node];
        int i = lo;
        for (; i + 16 <= hi; i += 16) {
            const int4 r0 = er[i + 4 * q + 0];
            const int4 r1 = er[i + 4 * q + 1];
            const int4 r2 = er[i + 4 * q + 2];
            const int4 r3 = er[i + 4 * q + 3];
            const u32x4 h0 = *(const u32x4*)(hb + (size_t)r0.x * DH + li * 8);
            const u32x4 h1 = *(const u32x4*)(hb + (size_t)r1.x * DH + li * 8);
            const u32x4 h2 = *(const u32x4*)(hb + (size_t)r2.x * DH + li * 8);
            const u32x4 h3 = *(const u32x4*)(hb + (size_t)r3.x * DH + li * 8);
            const float wp0 = __int_as_float(r0.y), ws0 = __int_as_float(r0.z);
            const float wp1 = __int_as_float(r1.y), ws1 = __int_as_float(r1.z);
            const float wp2 = __int_as_float(r2.y), ws2 = __int_as_float(r2.z);
            const float wp3 = __int_as_float(r3.y), ws3 = __int_as_float(r3.z);
#pragma unroll
            for (int d = 0; d < 4; ++d) {
                float l0 = bf16_lo(h0[d]), g0 = bf16_hi(h0[d]);
                float l1 = bf16_lo(h1[d]), g1 = bf16_hi(h1[d]);
                float l2 = bf16_lo(h2[d]), g2 = bf16_hi(h2[d]);
                float l3 = bf16_lo(h3[d]), g3 = bf16_hi(h3[d]);
                aa[2*d]   += wp0 * l0 + wp1 * l1 + wp2 * l2 + wp3 * l3;
                aa[2*d+1] += wp0 * g0 + wp1 * g1 + wp2 * g2 + wp3 * g3;
                rr[2*d]   += ws0 * l0 + ws1 * l1 + ws2 * l2 + ws3 * l3;
                rr[2*d+1] += ws0 * g0 + ws1 * g1 + ws2 * g2 + ws3 * g3;
            }
        }
        for (; i < hi; i += 4) {
            const int4 r0 = er[i + q];
            const u32x4 h0 = *(const u32x4*)(hb + (size_t)r0.x * DH + li * 8);
            const float wp0 = __int_as_float(r0.y), ws0 = __int_as_float(r0.z);
#pragma unroll
            for (int d = 0; d < 4; ++d) {
                float l0 = bf16_lo(h0[d]), g0 = bf16_hi(h0[d]);
                aa[2*d]   += wp0 * l0;
                aa[2*d+1] += wp0 * g0;
                rr[2*d]   += ws0 * l0;
                rr[2*d+1] += ws0 * g0;
            }
        }
    }
    // cross-quarter butterfly (uniform across wave; outside any divergence)
#pragma unroll
    for (int d = 0; d < 8; ++d) {
        aa[d] += __shfl_xor(aa[d], 16);
        aa[d] += __shfl_xor(aa[d], 32);
        rr[d] += __shfl_xor(rr[d], 16);
        rr[d] += __shfl_xor(rr[d], 32);
    }
    if (q == 0) {
        u32x4 pa;
        pa.x = cvt_pk_bf16(aa[0], aa[1]); pa.y = cvt_pk_bf16(aa[2], aa[3]);
        pa.z = cvt_pk_bf16(aa[4], aa[5]); pa.w = cvt_pk_bf16(aa[6], aa[7]);
        *(u32x4*)(agg_b + (size_t)node * DH + li * 8) = pa;
    } else if (q == 1) {
        u32x4 pr;
        pr.x = cvt_pk_bf16(rr[0], rr[1]); pr.y = cvt_pk_bf16(rr[2], rr[3]);
        pr.z = cvt_pk_bf16(rr[4], rr[5]); pr.w = cvt_pk_bf16(rr[6], rr[7]);
        *(u32x4*)(res_b + (size_t)node * DH + li * 8) = pr;
    }
}

// ---------------- hidden GEMM (bf16 in, bf16 out, bias+relu+res) ------------
__global__ __launch_bounds__(256) void mfma_hidden_kernel(
    const ushort_t* __restrict__ agg_b, const ushort_t* __restrict__ Bp,
    const float* __restrict__ bias, const ushort_t* __restrict__ res_b,
    ushort_t* __restrict__ hb_out)
{
    constexpr int CHN = DH / 32;                       // 4
    const int lane = threadIdx.x & 63;
    const int w    = threadIdx.x >> 6;
    const int r0   = blockIdx.y * 64;
    const int lr   = lane & 15;
    const int lq   = lane >> 4;

    bf16x8 bf[4][CHN];
#pragma unroll
    for (int t = 0; t < 4; ++t) {
        const ushort_t* p = agg_b + (size_t)(r0 + t * 16 + lr) * DH + lq * 8;
#pragma unroll
        for (int c = 0; c < CHN; ++c)
            bf[t][c] = *(const bf16x8*)(p + c * 32);
    }

#pragma unroll
    for (int g = 0; g < 2; ++g) {
        const int dt = g * 4 + w;
        f32x4 acc[4] = {f32x4{0,0,0,0}, f32x4{0,0,0,0}, f32x4{0,0,0,0}, f32x4{0,0,0,0}};
#pragma unroll
        for (int c = 0; c < CHN; ++c) {
            bf16x8 afrag = *(const bf16x8*)(Bp + ((size_t)(dt * CHN + c) * 64 + lane) * 8);
#pragma unroll
            for (int t = 0; t < 4; ++t)
                acc[t] = __builtin_amdgcn_mfma_f32_16x16x32_bf16(afrag, bf[t][c], acc[t], 0, 0, 0);
        }
        const int d0 = dt * 16 + lq * 4;
        const float4 b4 = *(const float4*)(bias + d0);
#pragma unroll
        for (int t = 0; t < 4; ++t) {
            const int node = r0 + t * 16 + lr;
            float v[4];
            v[0] = fmaxf(acc[t][0] + b4.x, 0.f);
            v[1] = fmaxf(acc[t][1] + b4.y, 0.f);
            v[2] = fmaxf(acc[t][2] + b4.z, 0.f);
            v[3] = fmaxf(acc[t][3] + b4.w, 0.f);
            const uint2 rw = *(const uint2*)(res_b + (size_t)node * DH + d0);
            v[0] += bf16_lo(rw.x); v[1] += bf16_hi(rw.x);
            v[2] += bf16_lo(rw.y); v[3] += bf16_hi(rw.y);
            uint2 pp;
            pp.x = cvt_pk_bf16(v[0], v[1]);
            pp.y = cvt_pk_bf16(v[2], v[3]);
            *(uint2*)(hb_out + (size_t)node * DH + d0) = pp;
        }
    }
}

// ---------------- output GEMM, 32-node blocks, LDS-staged stores ------------
__global__ __launch_bounds__(256) void mfma_out_kernel(
    const ushort_t* __restrict__ hb, const ushort_t* __restrict__ Bp,
    const float* __restrict__ bias, float* __restrict__ out)
{
    constexpr int CHN = DH / 32;                       // 4
    __shared__ float cst[32][260];                     // 33.3 KB
    const int lane = threadIdx.x & 63;
    const int w    = threadIdx.x >> 6;
    const int r0   = blockIdx.y * 32;
    const int lr   = lane & 15;
    const int lq   = lane >> 4;

    bf16x8 bf[2][CHN];
#pragma unroll
    for (int t = 0; t < 2; ++t) {
        const ushort_t* p = hb + (size_t)(r0 + t * 16 + lr) * DH + lq * 8;
#pragma unroll
        for (int c = 0; c < CHN; ++c)
            bf[t][c] = *(const bf16x8*)(p + c * 32);
    }

#pragma unroll
    for (int g = 0; g < 4; ++g) {
        const int dt = (blockIdx.x * 4 + g) * 4 + w;   // global 16-label tile
        f32x4 acc[2] = {f32x4{0,0,0,0}, f32x4{0,0,0,0}};
#pragma unroll
        for (int c = 0; c < CHN; ++c) {
            bf16x8 afrag = *(const bf16x8*)(Bp + ((size_t)(dt * CHN + c) * 64 + lane) * 8);
#pragma unroll
            for (int t = 0; t < 2; ++t)
                acc[t] = __builtin_amdgcn_mfma_f32_16x16x32_bf16(afrag, bf[t][c], acc[t], 0, 0, 0);
        }

        const int d0 = dt * 16 + lq * 4;               // global label index
        float bv[4];
        if (d0 + 3 < NL) {
            const float4 b4 = *(const float4*)(bias + d0);
            bv[0] = b4.x; bv[1] = b4.y; bv[2] = b4.z; bv[3] = b4.w;
        } else {
#pragma unroll
            for (int i = 0; i < 4; ++i) bv[i] = (d0 + i < NL) ? bias[d0 + i] : 0.f;
        }
        const int cl = ((g * 4 + w) * 16) + lq * 4;    // local col in the 256-wide tile
#pragma unroll
        for (int t = 0; t < 2; ++t) {
            const int rl = t * 16 + lr;
#pragma unroll
            for (int i = 0; i < 4; ++i)
                cst[rl][cl + i] = acc[t][i] + bv[i];
        }
    }
    __syncthreads();

    // store sweep: one 1024-B contiguous wave store per node row chunk.
    // Full-line nontemporal stores: out is write-once, never re-read ->
    // keep 200 MB of stream-out from thrashing L2/L3.
    const int colbase = blockIdx.x * 256;
    const int c = lane * 4;                            // local col (f32)
#pragma unroll
    for (int r = 0; r < 8; ++r) {
        const int rl = w * 8 + r;
        const int node = r0 + rl;
        if (node < N_NODES && colbase + c < NL) {
            f32x4 o4;
            o4.x = cst[rl][c]; o4.y = cst[rl][c + 1];
            o4.z = cst[rl][c + 2]; o4.w = cst[rl][c + 3];
            __builtin_nontemporal_store(o4, (f32x4*)(out + (size_t)node * NL + colbase + c));
        }
    }
}

// ---------------- launch ----------------

extern "C" void kernel_launch(void* const* d_in, const int* in_sizes, int n_in,
                              void* d_out, int out_size, void* d_ws, size_t ws_size,
                              hipStream_t stream) {
    const float* x      = (const float*)d_in[0];
    const int*   src    = (const int*)d_in[1];
    const int*   dst    = (const int*)d_in[2];
    const float* self_w = (const float*)d_in[3];
    const float* ppi_w  = (const float*)d_in[4];
    const float* W_in   = (const float*)d_in[5];
    const float* b_in   = (const float*)d_in[6];
    const float* W1     = (const float*)d_in[7];
    const float* b1     = (const float*)d_in[8];
    const float* W2     = (const float*)d_in[9];
    const float* b2     = (const float*)d_in[10];
    const float* W_out  = (const float*)d_in[11];
    const float* b_out  = (const float*)d_in[12];
    float* out = (float*)d_out;

    char* ws = (char*)d_ws;
    size_t o = 0;
    auto alloc = [&](size_t bytes) { void* p = ws + o; o += (bytes + 255) & ~(size_t)255; return p; };

    ushort_t* hb     = (ushort_t*)alloc((size_t)M_PAD * DH * 2);   // 12.8 MB
    ushort_t* hb2    = (ushort_t*)alloc((size_t)M_PAD * DH * 2);   // 12.8 MB
    ushort_t* agg_b  = (ushort_t*)alloc((size_t)M_PAD * DH * 2);   // 12.8 MB
    ushort_t* res_b  = (ushort_t*)alloc((size_t)M_PAD * DH * 2);   // 12.8 MB
    int*      degz   = (int*)alloc((size_t)(N_NODES + 1) * 4);     // deg + gcount
    int*      gcount = degz + N_NODES;
    int*      off_s  = (int*)alloc((size_t)N_NODES * 4);
    int*      off_pe = (int*)alloc((size_t)N_NODES * 4);
    int*      rank   = (int*)alloc((size_t)N_EDGES * 4);           // 3.2 MB
    int4*     er     = (int4*)alloc((size_t)E_PAD * 16);           // 16 MB records
    ushort_t* Bp_in  = (ushort_t*)alloc((size_t)T_IN * 8 * 2);
    ushort_t* Bp_1   = (ushort_t*)alloc((size_t)T_L * 8 * 2);
    ushort_t* Bp_2   = (ushort_t*)alloc((size_t)T_L * 8 * 2);
    ushort_t* Bp_out = (ushort_t*)alloc((size_t)T_OUT * 8 * 2);

    // CSR build: deg+rank count (+ fused weight pack), wave-atomic alloc
    (void)hipMemsetAsync(degz, 0, (size_t)(N_NODES + 1) * 4, stream);
    count_pack_kernel<<<EB + PB, 256, 0, stream>>>(dst, degz, rank, W_in, W1, W2, W_out,
                                                   Bp_in, Bp_1, Bp_2, Bp_out);
    alloc_kernel<<<(N_NODES + 255) / 256, 256, 0, stream>>>(degz, gcount, off_s, off_pe, er);

    // fused scatter + input GEMM (independent work overlapped in one dispatch)
    scatter_in_kernel<<<EB + MB_IN, 256, 0, stream>>>(dst, src, self_w, ppi_w, off_s, rank, er,
                                                      x, Bp_in, b_in, hb);

    const dim3 g_h(1, M_PAD / 64);   // 782 blocks
    const dim3 g_o(4, M_PAD / 32);   // out GEMM: 4 x 256-label chunks, 32-node rows

    // layer 1
    aggregate_kernel<<<M_PAD / 4, 256, 0, stream>>>(hb, off_s, off_pe, er, agg_b, res_b);
    mfma_hidden_kernel<<<g_h, 256, 0, stream>>>(agg_b, Bp_1, b1, res_b, hb2);

    // layer 2
    aggregate_kernel<<<M_PAD / 4, 256, 0, stream>>>(hb2, off_s, off_pe, er, agg_b, res_b);
    mfma_hidden_kernel<<<g_h, 256, 0, stream>>>(agg_b, Bp_2, b2, res_b, hb);

    // output linear: out = hb @ W_out + b_out  (LDS-staged nontemporal stores)
    mfma_out_kernel<<<g_o, 256, 0, stream>>>(hb, Bp_out, b_out, out);
}